// Round 4
// baseline (85.336 us; speedup 1.0000x reference)
//
#include <hip/hip_runtime.h>
#include <math.h>

#define FAR_DELTA 1e10f
#define TRANS_EPS 1e-10f
#define S 48

// DPP move: returns src moved per CTRL; invalid source lanes yield `old`.
template<int CTRL>
__device__ __forceinline__ float dppf(float x, float old) {
    return __int_as_float(__builtin_amdgcn_update_dpp(
        __float_as_int(old), __float_as_int(x), CTRL, 0xF, 0xF, false));
}

// Per-lane register tile: 3 samples of one ray (16 lanes per ray).
struct Regs {
    float x0,y0,z0,x1,y1,z1,x2,y2,z2;
    float d0,d1,d2;
    float r0,g0,b0,r1,g1,b1,r2,g2,b2;
};

__device__ __forceinline__ void load_ray(Regs& R,
        const float* __restrict__ xyz, const float* __restrict__ dens,
        const float* __restrict__ rgb, long long ray, int li)
{
    const size_t base = (size_t)ray * S + (size_t)li * 3;
    const float* px = xyz + base * 3;
    R.x0 = px[0]; R.y0 = px[1]; R.z0 = px[2];
    R.x1 = px[3]; R.y1 = px[4]; R.z1 = px[5];
    R.x2 = px[6]; R.y2 = px[7]; R.z2 = px[8];
    const float* pd = dens + base;
    R.d0 = pd[0]; R.d1 = pd[1]; R.d2 = pd[2];
    const float* pc = rgb + base * 3;
    R.r0 = pc[0]; R.g0 = pc[1]; R.b0 = pc[2];
    R.r1 = pc[3]; R.g1 = pc[4]; R.b1 = pc[5];
    R.r2 = pc[6]; R.g2 = pc[7]; R.b2 = pc[8];
}

__device__ __forceinline__ void compute_ray(const Regs& R,
        const float* __restrict__ bg, float* __restrict__ out_rgb,
        float* __restrict__ out_acc, float* __restrict__ out_w,
        long long ray, int li)
{
    // next lane's first sample position (row_shl:1)
    float xn = dppf<0x101>(R.x0, 0.f);
    float yn = dppf<0x101>(R.y0, 0.f);
    float zn = dppf<0x101>(R.z0, 0.f);

    float dx = R.x1 - R.x0, dy = R.y1 - R.y0, dz = R.z1 - R.z0;
    float delta0 = sqrtf(dx * dx + dy * dy + dz * dz);
    dx = R.x2 - R.x1; dy = R.y2 - R.y1; dz = R.z2 - R.z1;
    float delta1 = sqrtf(dx * dx + dy * dy + dz * dz);
    float delta2;
    if (li == 15) {
        delta2 = FAR_DELTA;
    } else {
        dx = xn - R.x2; dy = yn - R.y2; dz = zn - R.z2;
        delta2 = sqrtf(dx * dx + dy * dy + dz * dz);
    }

    float e0 = __expf(-fmaxf(R.d0, 0.f) * delta0);
    float e1 = __expf(-fmaxf(R.d1, 0.f) * delta1);
    float e2 = __expf(-fmaxf(R.d2, 0.f) * delta2);
    float a0 = 1.f - e0, a1 = 1.f - e1, a2 = 1.f - e2;
    float q0 = e0 + TRANS_EPS, q1 = e1 + TRANS_EPS, q2 = e2 + TRANS_EPS;

    // exclusive product scan of m = q0*q1*q2 across the 16-lane row
    float m = q0 * q1 * q2;
    float t = dppf<0x111>(m, 1.f);   // row_shr:1 (lane0 -> 1)
    t *= dppf<0x111>(t, 1.f);
    t *= dppf<0x112>(t, 1.f);
    t *= dppf<0x114>(t, 1.f);
    t *= dppf<0x118>(t, 1.f);

    float T0 = t, T1 = t * q0, T2 = T1 * q1;
    float w0 = a0 * T0, w1 = a1 * T1, w2 = a2 * T2;

    float* pw = out_w + (size_t)ray * S + (size_t)li * 3;
    __builtin_nontemporal_store(w0, pw + 0);
    __builtin_nontemporal_store(w1, pw + 1);
    __builtin_nontemporal_store(w2, pw + 2);

    float sr = w0 * R.r0 + w1 * R.r1 + w2 * R.r2;
    float sg = w0 * R.g0 + w1 * R.g1 + w2 * R.g2;
    float sb = w0 * R.b0 + w1 * R.b1 + w2 * R.b2;
    float sw = w0 + w1 + w2;

    // 16-lane butterfly: xor1, xor2, xor4 (half-mirror), xor8 (mirror)
    sr += dppf<0xB1>(sr, 0.f);  sg += dppf<0xB1>(sg, 0.f);
    sb += dppf<0xB1>(sb, 0.f);  sw += dppf<0xB1>(sw, 0.f);
    sr += dppf<0x4E>(sr, 0.f);  sg += dppf<0x4E>(sg, 0.f);
    sb += dppf<0x4E>(sb, 0.f);  sw += dppf<0x4E>(sw, 0.f);
    sr += dppf<0x141>(sr, 0.f); sg += dppf<0x141>(sg, 0.f);
    sb += dppf<0x141>(sb, 0.f); sw += dppf<0x141>(sw, 0.f);
    sr += dppf<0x140>(sr, 0.f); sg += dppf<0x140>(sg, 0.f);
    sb += dppf<0x140>(sb, 0.f); sw += dppf<0x140>(sw, 0.f);

    if (li == 0) {
        const float* pb = bg + (size_t)ray * 3;
        float inv = 1.f - sw;
        float* po = out_rgb + (size_t)ray * 3;
        __builtin_nontemporal_store(sr + pb[0] * inv, po + 0);
        __builtin_nontemporal_store(sg + pb[1] * inv, po + 1);
        __builtin_nontemporal_store(sb + pb[2] * inv, po + 2);
        __builtin_nontemporal_store(sw, out_acc + ray);
    }
}

// Persistent grid-stride over 16-ray tiles; register double-buffered pipeline.
__global__ __launch_bounds__(256) void nerf_render_kernel(
    const float* __restrict__ xyz,   // [N, 48, 3]
    const float* __restrict__ dens,  // [N, 48]
    const float* __restrict__ rgb,   // [N, 48, 3]
    const float* __restrict__ bg,    // [N, 3]
    float* __restrict__ out_rgb,     // [N, 3]
    float* __restrict__ out_acc,     // [N]
    float* __restrict__ out_w,       // [N, 48]
    int N, int ntiles)
{
    const int li    = threadIdx.x & 15;   // lane within ray (DPP row)
    const int group = threadIdx.x >> 4;   // ray-within-tile, 0..15
    const int stride = gridDim.x;

    long long tCur = blockIdx.x;
    if (tCur >= ntiles) return;

    Regs A, B;
    long long rayA = tCur * 16 + group;
    if (rayA < N) load_ray(A, xyz, dens, rgb, rayA, li);

    for (;;) {
        // ---- half 1: prefetch next into B, compute A ----
        long long tNext = tCur + stride;
        bool hn = tNext < ntiles;
        long long rayB = tNext * 16 + group;
        if (hn && rayB < N) load_ray(B, xyz, dens, rgb, rayB, li);
        if (rayA < N) compute_ray(A, bg, out_rgb, out_acc, out_w, rayA, li);
        if (!hn) break;
        tCur = tNext;

        // ---- half 2: prefetch next into A, compute B ----
        tNext = tCur + stride;
        hn = tNext < ntiles;
        rayA = tNext * 16 + group;
        if (hn && rayA < N) load_ray(A, xyz, dens, rgb, rayA, li);
        if (rayB < N) compute_ray(B, bg, out_rgb, out_acc, out_w, rayB, li);
        if (!hn) break;
        tCur = tNext;
    }
}

extern "C" void kernel_launch(void* const* d_in, const int* in_sizes, int n_in,
                              void* d_out, int out_size, void* d_ws, size_t ws_size,
                              hipStream_t stream) {
    const float* xyz  = (const float*)d_in[0];   // [N,48,3]
    const float* dens = (const float*)d_in[1];   // [N,48,1]
    const float* rgb  = (const float*)d_in[2];   // [N,48,3]
    const float* bg   = (const float*)d_in[3];   // [N,3]

    const int N = in_sizes[3] / 3;               // S = 48

    float* out     = (float*)d_out;
    float* out_rgb = out;                  // N*3
    float* out_acc = out + (size_t)N * 3;  // N
    float* out_w   = out + (size_t)N * 4;  // N*48

    const int ntiles = (N + 15) / 16;
    const int grid = ntiles < 2048 ? ntiles : 2048;
    nerf_render_kernel<<<grid, 256, 0, stream>>>(xyz, dens, rgb, bg,
                                                 out_rgb, out_acc, out_w,
                                                 N, ntiles);
}

// Round 5
// 81.059 us; speedup vs baseline: 1.0528x; 1.0528x over previous
//
#include <hip/hip_runtime.h>
#include <math.h>

#define FAR_DELTA 1e10f
#define TRANS_EPS 1e-10f
#define S 48

// DPP move: returns src moved per CTRL; invalid source lanes yield `old`.
template<int CTRL>
__device__ __forceinline__ float dppf(float x, float old) {
    return __int_as_float(__builtin_amdgcn_update_dpp(
        __float_as_int(old), __float_as_int(x), CTRL, 0xF, 0xF, false));
}

// 12 active lanes per 16-lane DPP row, 4 samples per lane (S=48).
// All global accesses are aligned float4: xyz/rgb 3 each, dens 1, weights 1.
__global__ __launch_bounds__(256) void nerf_render_kernel(
    const float* __restrict__ xyz,   // [N, 48, 3]
    const float* __restrict__ dens,  // [N, 48]
    const float* __restrict__ rgb,   // [N, 48, 3]
    const float* __restrict__ bg,    // [N, 3]
    float* __restrict__ out_rgb,     // [N, 3]
    float* __restrict__ out_acc,     // [N]
    float* __restrict__ out_w,       // [N, 48]
    int N)
{
    const int tid = blockIdx.x * 256 + threadIdx.x;
    const int li  = threadIdx.x & 15;   // lane within DPP row
    const long long ray = tid >> 4;
    if (ray >= N) return;
    const bool act = (li < 12);

    float4 P0 = make_float4(0,0,0,0), P1 = P0, P2 = P0;  // 12 xyz floats
    float4 C0 = P0, C1 = P0, C2 = P0;                    // 12 rgb floats
    float4 D  = P0;                                      // 4 densities

    if (act) {
        const float4* px = (const float4*)(xyz + (size_t)ray * (S * 3)) + li * 3;
        P0 = px[0]; P1 = px[1]; P2 = px[2];
        D = *((const float4*)(dens + (size_t)ray * S) + li);
        const float4* pc = (const float4*)(rgb + (size_t)ray * (S * 3)) + li * 3;
        C0 = pc[0]; C1 = pc[1]; C2 = pc[2];
    }

    // samples: s0=(P0.x,P0.y,P0.z) s1=(P0.w,P1.x,P1.y) s2=(P1.z,P1.w,P2.x) s3=(P2.y,P2.z,P2.w)
    // next lane's first sample position (row_shl:1 = 0x101)
    float xn = dppf<0x101>(P0.x, 0.f);
    float yn = dppf<0x101>(P0.y, 0.f);
    float zn = dppf<0x101>(P0.z, 0.f);

    float dx, dy, dz;
    dx = P0.w - P0.x; dy = P1.x - P0.y; dz = P1.y - P0.z;
    float delta0 = sqrtf(dx * dx + dy * dy + dz * dz);
    dx = P1.z - P0.w; dy = P1.w - P1.x; dz = P2.x - P1.y;
    float delta1 = sqrtf(dx * dx + dy * dy + dz * dz);
    dx = P2.y - P1.z; dy = P2.z - P1.w; dz = P2.w - P2.x;
    float delta2 = sqrtf(dx * dx + dy * dy + dz * dz);
    float delta3;
    if (li == 11) {
        delta3 = FAR_DELTA;
    } else {
        dx = xn - P2.y; dy = yn - P2.z; dz = zn - P2.w;
        delta3 = sqrtf(dx * dx + dy * dy + dz * dz);
    }

    float e0 = __expf(-fmaxf(D.x, 0.f) * delta0);
    float e1 = __expf(-fmaxf(D.y, 0.f) * delta1);
    float e2 = __expf(-fmaxf(D.z, 0.f) * delta2);
    float e3 = __expf(-fmaxf(D.w, 0.f) * delta3);
    float a0 = 1.f - e0, a1 = 1.f - e1, a2 = 1.f - e2, a3 = 1.f - e3;
    float q0 = e0 + TRANS_EPS, q1 = e1 + TRANS_EPS;
    float q2 = e2 + TRANS_EPS, q3 = e3 + TRANS_EPS;

    // exclusive product scan of m = q0*q1*q2*q3 across the row (lanes 0..11)
    float m = (q0 * q1) * (q2 * q3);
    float t = dppf<0x111>(m, 1.f);   // row_shr:1 (lane0 -> 1)
    t *= dppf<0x111>(t, 1.f);
    t *= dppf<0x112>(t, 1.f);
    t *= dppf<0x114>(t, 1.f);
    t *= dppf<0x118>(t, 1.f);

    float T0 = t, T1 = t * q0, T2 = T1 * q1, T3 = T2 * q2;
    float w0 = a0 * T0, w1 = a1 * T1, w2 = a2 * T2, w3 = a3 * T3;

    if (act) {
        float4 W = make_float4(w0, w1, w2, w3);
        *((float4*)(out_w + (size_t)ray * S) + li) = W;
    }

    float sr = 0.f, sg = 0.f, sb = 0.f, sw = 0.f;
    if (act) {
        // rgb: s0=(C0.x,C0.y,C0.z) s1=(C0.w,C1.x,C1.y) s2=(C1.z,C1.w,C2.x) s3=(C2.y,C2.z,C2.w)
        sr = w0 * C0.x + w1 * C0.w + w2 * C1.z + w3 * C2.y;
        sg = w0 * C0.y + w1 * C1.x + w2 * C1.w + w3 * C2.z;
        sb = w0 * C0.z + w1 * C1.y + w2 * C2.x + w3 * C2.w;
        sw = w0 + w1 + w2 + w3;
    }

    // 16-lane butterfly (idle lanes contribute 0): xor1, xor2, xor4, xor8
    sr += dppf<0xB1>(sr, 0.f);  sg += dppf<0xB1>(sg, 0.f);
    sb += dppf<0xB1>(sb, 0.f);  sw += dppf<0xB1>(sw, 0.f);
    sr += dppf<0x4E>(sr, 0.f);  sg += dppf<0x4E>(sg, 0.f);
    sb += dppf<0x4E>(sb, 0.f);  sw += dppf<0x4E>(sw, 0.f);
    sr += dppf<0x141>(sr, 0.f); sg += dppf<0x141>(sg, 0.f);
    sb += dppf<0x141>(sb, 0.f); sw += dppf<0x141>(sw, 0.f);
    sr += dppf<0x140>(sr, 0.f); sg += dppf<0x140>(sg, 0.f);
    sb += dppf<0x140>(sb, 0.f); sw += dppf<0x140>(sw, 0.f);

    if (li == 0) {
        const float* pb = bg + (size_t)ray * 3;
        float inv = 1.f - sw;
        float* po = out_rgb + (size_t)ray * 3;
        po[0] = sr + pb[0] * inv;
        po[1] = sg + pb[1] * inv;
        po[2] = sb + pb[2] * inv;
        out_acc[ray] = sw;
    }
}

extern "C" void kernel_launch(void* const* d_in, const int* in_sizes, int n_in,
                              void* d_out, int out_size, void* d_ws, size_t ws_size,
                              hipStream_t stream) {
    const float* xyz  = (const float*)d_in[0];   // [N,48,3]
    const float* dens = (const float*)d_in[1];   // [N,48,1]
    const float* rgb  = (const float*)d_in[2];   // [N,48,3]
    const float* bg   = (const float*)d_in[3];   // [N,3]

    const int N = in_sizes[3] / 3;               // S = 48

    float* out     = (float*)d_out;
    float* out_rgb = out;                  // N*3
    float* out_acc = out + (size_t)N * 3;  // N
    float* out_w   = out + (size_t)N * 4;  // N*48

    // 16 lanes (12 active) per ray -> 16 rays per 256-thread block.
    const int grid = (N + 15) / 16;
    nerf_render_kernel<<<grid, 256, 0, stream>>>(xyz, dens, rgb, bg,
                                                 out_rgb, out_acc, out_w, N);
}

// Round 6
// 74.864 us; speedup vs baseline: 1.1399x; 1.0828x over previous
//
#include <hip/hip_runtime.h>
#include <math.h>

#define FAR_DELTA 1e10f
#define TRANS_EPS 1e-10f

// DPP move: returns src moved per CTRL; invalid source lanes yield `old`.
template<int CTRL>
__device__ __forceinline__ float dppf(float x, float old) {
    return __int_as_float(__builtin_amdgcn_update_dpp(
        __float_as_int(old), __float_as_int(x), CTRL, 0xF, 0xF, false));
}

// 16 lanes per ray (one DPP row), 3 samples per lane (S=48), 4 rays per wave.
// R2 structure (78.5us champion) + nontemporal output stores (anti-pollution).
__global__ __launch_bounds__(256) void nerf_render_kernel(
    const float* __restrict__ xyz,   // [N, 48, 3]
    const float* __restrict__ dens,  // [N, 48]
    const float* __restrict__ rgb,   // [N, 48, 3]
    const float* __restrict__ bg,    // [N, 3]
    float* __restrict__ out_rgb,     // [N, 3]
    float* __restrict__ out_acc,     // [N]
    float* __restrict__ out_w,       // [N, 48]
    int N)
{
    const int tid = blockIdx.x * 256 + threadIdx.x;
    const int li  = threadIdx.x & 15;          // lane within ray group
    const int ray = tid >> 4;
    if (ray >= N) return;

    const size_t base = (size_t)ray * 48 + (size_t)li * 3;  // first sample idx

    // ---- loads: 9 pos floats, 3 densities, 9 rgb floats per lane ----
    const float* px = xyz + base * 3;
    float x0 = px[0], y0 = px[1], z0 = px[2];
    float x1 = px[3], y1 = px[4], z1 = px[5];
    float x2 = px[6], y2 = px[7], z2 = px[8];

    const float* pd = dens + base;
    float d0 = pd[0], d1 = pd[1], d2 = pd[2];

    const float* pc = rgb + base * 3;
    float r0 = pc[0], g0 = pc[1], b0 = pc[2];
    float r1 = pc[3], g1 = pc[4], b1 = pc[5];
    float r2 = pc[6], g2 = pc[7], b2 = pc[8];

    // ---- next lane's first sample position (row_shl:1 = 0x101) ----
    float xn = dppf<0x101>(x0, 0.f);
    float yn = dppf<0x101>(y0, 0.f);
    float zn = dppf<0x101>(z0, 0.f);

    // ---- deltas ----
    float dx, dy, dz;
    dx = x1 - x0; dy = y1 - y0; dz = z1 - z0;
    float delta0 = sqrtf(dx * dx + dy * dy + dz * dz);
    dx = x2 - x1; dy = y2 - y1; dz = z2 - z1;
    float delta1 = sqrtf(dx * dx + dy * dy + dz * dz);
    float delta2;
    if (li == 15) {
        delta2 = FAR_DELTA;
    } else {
        dx = xn - x2; dy = yn - y2; dz = zn - z2;
        delta2 = sqrtf(dx * dx + dy * dy + dz * dz);
    }

    // ---- alphas: e = exp(-relu(d)*delta); alpha = 1-e; q = e + eps ----
    float e0 = __expf(-fmaxf(d0, 0.f) * delta0);
    float e1 = __expf(-fmaxf(d1, 0.f) * delta1);
    float e2 = __expf(-fmaxf(d2, 0.f) * delta2);
    float a0 = 1.f - e0, a1 = 1.f - e1, a2 = 1.f - e2;
    float q0 = e0 + TRANS_EPS, q1 = e1 + TRANS_EPS, q2 = e2 + TRANS_EPS;

    // ---- exclusive product scan of m = q0*q1*q2 across the 16-lane row ----
    float m = q0 * q1 * q2;
    float t = dppf<0x111>(m, 1.f);   // row_shr:1 (lane0 -> 1)
    t *= dppf<0x111>(t, 1.f);
    t *= dppf<0x112>(t, 1.f);
    t *= dppf<0x114>(t, 1.f);
    t *= dppf<0x118>(t, 1.f);

    // ---- per-sample transmittance & weights ----
    float T0 = t, T1 = t * q0, T2 = T1 * q1;
    float w0 = a0 * T0, w1 = a1 * T1, w2 = a2 * T2;

    float* pw = out_w + base;
    __builtin_nontemporal_store(w0, pw + 0);
    __builtin_nontemporal_store(w1, pw + 1);
    __builtin_nontemporal_store(w2, pw + 2);

    // ---- per-lane partial sums, then 16-lane DPP butterfly reduce ----
    float sr = w0 * r0 + w1 * r1 + w2 * r2;
    float sg = w0 * g0 + w1 * g1 + w2 * g2;
    float sb = w0 * b0 + w1 * b1 + w2 * b2;
    float sw = w0 + w1 + w2;

    // xor1: quad_perm[1,0,3,2]=0xB1; xor2: quad_perm[2,3,0,1]=0x4E;
    // xor4: row_half_mirror=0x141; xor8: row_mirror=0x140
    sr += dppf<0xB1>(sr, 0.f); sg += dppf<0xB1>(sg, 0.f);
    sb += dppf<0xB1>(sb, 0.f); sw += dppf<0xB1>(sw, 0.f);
    sr += dppf<0x4E>(sr, 0.f); sg += dppf<0x4E>(sg, 0.f);
    sb += dppf<0x4E>(sb, 0.f); sw += dppf<0x4E>(sw, 0.f);
    sr += dppf<0x141>(sr, 0.f); sg += dppf<0x141>(sg, 0.f);
    sb += dppf<0x141>(sb, 0.f); sw += dppf<0x141>(sw, 0.f);
    sr += dppf<0x140>(sr, 0.f); sg += dppf<0x140>(sg, 0.f);
    sb += dppf<0x140>(sb, 0.f); sw += dppf<0x140>(sw, 0.f);

    if (li == 0) {
        const float* pb = bg + (size_t)ray * 3;
        float inv = 1.f - sw;
        float* po = out_rgb + (size_t)ray * 3;
        __builtin_nontemporal_store(sr + pb[0] * inv, po + 0);
        __builtin_nontemporal_store(sg + pb[1] * inv, po + 1);
        __builtin_nontemporal_store(sb + pb[2] * inv, po + 2);
        __builtin_nontemporal_store(sw, out_acc + ray);
    }
}

extern "C" void kernel_launch(void* const* d_in, const int* in_sizes, int n_in,
                              void* d_out, int out_size, void* d_ws, size_t ws_size,
                              hipStream_t stream) {
    const float* xyz  = (const float*)d_in[0];   // [N,48,3]
    const float* dens = (const float*)d_in[1];   // [N,48,1]
    const float* rgb  = (const float*)d_in[2];   // [N,48,3]
    const float* bg   = (const float*)d_in[3];   // [N,3]

    const int N = in_sizes[3] / 3;               // S = in_sizes[1]/N = 48

    float* out     = (float*)d_out;
    float* out_rgb = out;                  // N*3
    float* out_acc = out + (size_t)N * 3;  // N
    float* out_w   = out + (size_t)N * 4;  // N*48

    // 16 threads per ray -> 16 rays per 256-thread block.
    const int grid = (N + 15) / 16;
    nerf_render_kernel<<<grid, 256, 0, stream>>>(xyz, dens, rgb, bg,
                                                 out_rgb, out_acc, out_w, N);
}